// Round 1
// baseline (371.551 us; speedup 1.0000x reference)
//
#include <hip/hip_runtime.h>

// Problem dims (fixed by reference): P=64, CIN=16 (z), COUT=16 (v), T=4 (a/b), N=32 (i,j), X=64
#define NP    64
#define NCIN  16
#define NCOUT 16
#define NT    4
#define NN    32
#define NX    64

typedef __attribute__((ext_vector_type(8))) __bf16 bf16x8;
typedef __attribute__((ext_vector_type(4))) float  f32x4;

// pack two fp32 -> packed bf16 pair (round-half-up via +0x8000, then take high 16 bits)
__device__ __forceinline__ unsigned pk_bf16(float lo, float hi) {
    unsigned ulo = __float_as_uint(lo) + 0x8000u;
    unsigned uhi = __float_as_uint(hi) + 0x8000u;
    // result = [ulo.b2, ulo.b3, uhi.b2, uhi.b3] = bf16(lo) | bf16(hi)<<16
    return __builtin_amdgcn_perm(uhi, ulo, 0x07060302u);
}

// Block = (p, i): 256 threads = 4 waves; wave w handles j = w*8 .. w*8+7.
// Per atom (p,i,j): Q[z,ab] = sum_x FW[z,x] * (PFi[a,x]*PFj[b,x]) via 2x mfma 16x16x32 bf16,
// then out[v] = sum_{z,ab} Q * WW[z,ab,v] via per-lane fp32 fma + 64-lane segmented reduce.
__global__ __launch_bounds__(256) void higher_point_kernel(
    const float* __restrict__ FW,   // (P, CIN, N, N, X)
    const float* __restrict__ PF,   // (P, T, N, X)
    const float* __restrict__ W0,   // (T, CIN, COUT)
    const float* __restrict__ W1,   // (T, CIN, COUT)
    const float* __restrict__ BIAS, // (COUT,1,1)
    float* __restrict__ OUT)        // (P, COUT, N, N)
{
    __shared__ float pf_lds[NT * NN * NX]; // 32 KB, PF[p] staged linearly [t][j][x]

    const int bx   = blockIdx.x;
    const int p    = bx >> 5;
    const int i    = bx & 31;
    const int tid  = threadIdx.x;
    const int lane = tid & 63;
    const int wave = tid >> 6;

    // ---- stage PF[p] (8192 floats) into LDS, coalesced float4 ----
    {
        const float4* pf_g = (const float4*)(PF + p * (NT * NN * NX));
        float4* pf_s = (float4*)pf_lds;
        #pragma unroll
        for (int k = 0; k < 8; ++k) pf_s[tid + k * 256] = pf_g[tid + k * 256];
    }
    __syncthreads();

    const int c = lane & 15;  // A-frag row (z) / B-frag col (ab) / D col (ab)
    const int q = lane >> 4;  // quad: k-block for A/B frags, row-block for D
    const int aIdx = c >> 2;  // ab = a*4 + b
    const int bIdx = c & 3;

    // ---- WW preload: ww[r][v] = w0[a, z=q*4+r, v] * w1[b, z=q*4+r, v]  (64 regs) ----
    float ww[4][16];
    #pragma unroll
    for (int r = 0; r < 4; ++r) {
        const int z = q * 4 + r;
        const float4* w0r = (const float4*)(W0 + (aIdx * NCIN + z) * NCOUT);
        const float4* w1r = (const float4*)(W1 + (bIdx * NCIN + z) * NCOUT);
        #pragma unroll
        for (int t4i = 0; t4i < 4; ++t4i) {
            float4 x0 = w0r[t4i], x1 = w1r[t4i];
            ww[r][t4i * 4 + 0] = x0.x * x1.x;
            ww[r][t4i * 4 + 1] = x0.y * x1.y;
            ww[r][t4i * 4 + 2] = x0.z * x1.z;
            ww[r][t4i * 4 + 3] = x0.w * x1.w;
        }
    }

    const float biasv = BIAS[lane >> 2]; // v = lane>>2 after the reduce

    // ---- PF_i slice (fixed per block): a=aIdx, x = q*8+e (half0) / +32 (half1) ----
    float pfi0[8], pfi1[8];
    {
        const float* base = pf_lds + (aIdx * NN + i) * NX + q * 8;
        #pragma unroll
        for (int e = 0; e < 8; ++e) { pfi0[e] = base[e]; pfi1[e] = base[32 + e]; }
    }

    // ---- FW row base for this lane: z = c, lane's x-offset q*8 ----
    const float* fw_row = FW + ((p * NCIN + c) * (NN * NN) + i * NN) * NX + q * 8;

    const int j0 = wave * 8;

    // software-pipelined FW loads (4 x dwordx4 per atom per lane = the whole HBM stream)
    float4 nf0a, nf0b, nf1a, nf1b;
    {
        const float* rb = fw_row + j0 * NX;
        nf0a = ((const float4*)rb)[0];
        nf0b = ((const float4*)rb)[1];
        nf1a = ((const float4*)(rb + 32))[0];
        nf1b = ((const float4*)(rb + 32))[1];
    }

    for (int jj = 0; jj < 8; ++jj) {
        const int j = j0 + jj;
        float4 f0a = nf0a, f0b = nf0b, f1a = nf1a, f1b = nf1b;
        if (jj < 7) {
            const float* rb = fw_row + (j + 1) * NX;
            nf0a = ((const float4*)rb)[0];
            nf0b = ((const float4*)rb)[1];
            nf1a = ((const float4*)(rb + 32))[0];
            nf1b = ((const float4*)(rb + 32))[1];
        }

        // PF_j slice from LDS: b=bIdx, x = q*8+e (+32)
        float pfj0[8], pfj1[8];
        {
            const float* base = pf_lds + (bIdx * NN + j) * NX + q * 8;
            #pragma unroll
            for (int e = 0; e < 8; ++e) { pfj0[e] = base[e]; pfj1[e] = base[32 + e]; }
        }

        // A-frags: FW[z=c][x=q*8+e]  (halves x:0..31 / 32..63)
        union { unsigned u[4]; bf16x8 v; } A0, A1, B0, B1;
        A0.u[0] = pk_bf16(f0a.x, f0a.y); A0.u[1] = pk_bf16(f0a.z, f0a.w);
        A0.u[2] = pk_bf16(f0b.x, f0b.y); A0.u[3] = pk_bf16(f0b.z, f0b.w);
        A1.u[0] = pk_bf16(f1a.x, f1a.y); A1.u[1] = pk_bf16(f1a.z, f1a.w);
        A1.u[2] = pk_bf16(f1b.x, f1b.y); A1.u[3] = pk_bf16(f1b.z, f1b.w);

        // B-frags: R[ab=c][x=q*8+e] = PFi[a,x]*PFj[b,x]
        float r0[8], r1[8];
        #pragma unroll
        for (int e = 0; e < 8; ++e) { r0[e] = pfi0[e] * pfj0[e]; r1[e] = pfi1[e] * pfj1[e]; }
        B0.u[0] = pk_bf16(r0[0], r0[1]); B0.u[1] = pk_bf16(r0[2], r0[3]);
        B0.u[2] = pk_bf16(r0[4], r0[5]); B0.u[3] = pk_bf16(r0[6], r0[7]);
        B1.u[0] = pk_bf16(r1[0], r1[1]); B1.u[1] = pk_bf16(r1[2], r1[3]);
        B1.u[2] = pk_bf16(r1[4], r1[5]); B1.u[3] = pk_bf16(r1[6], r1[7]);

        // Q[z,ab] accumulate (fp32 C-regs). D: col = lane&15 = ab, row z = q*4 + reg.
        f32x4 acc = {0.f, 0.f, 0.f, 0.f};
        acc = __builtin_amdgcn_mfma_f32_16x16x32_bf16(A0.v, B0.v, acc, 0, 0, 0);
        acc = __builtin_amdgcn_mfma_f32_16x16x32_bf16(A1.v, B1.v, acc, 0, 0, 0);

        // phase 3: per-lane partial over its 4 (z,ab) cells
        float partial[16];
        #pragma unroll
        for (int v = 0; v < 16; ++v)
            partial[v] = acc[0] * ww[0][v] + acc[1] * ww[1][v]
                       + acc[2] * ww[2][v] + acc[3] * ww[3][v];

        // segmented butterfly reduce 64 lanes x 16 vals -> lane holds v = lane>>2
        const bool b5 = (lane & 32) != 0;
        const bool b4 = (lane & 16) != 0;
        const bool b3 = (lane & 8)  != 0;
        const bool b2 = (lane & 4)  != 0;

        float t8[8];
        #pragma unroll
        for (int k = 0; k < 8; ++k) {
            float mine   = b5 ? partial[k + 8] : partial[k];
            float theirs = b5 ? partial[k]     : partial[k + 8];
            t8[k] = mine + __shfl_xor(theirs, 32, 64);
        }
        float t4[4];
        #pragma unroll
        for (int k = 0; k < 4; ++k) {
            float mine   = b4 ? t8[k + 4] : t8[k];
            float theirs = b4 ? t8[k]     : t8[k + 4];
            t4[k] = mine + __shfl_xor(theirs, 16, 64);
        }
        float t2[2];
        #pragma unroll
        for (int k = 0; k < 2; ++k) {
            float mine   = b3 ? t4[k + 2] : t4[k];
            float theirs = b3 ? t4[k]     : t4[k + 2];
            t2[k] = mine + __shfl_xor(theirs, 8, 64);
        }
        float mine1   = b2 ? t2[1] : t2[0];
        float theirs1 = b2 ? t2[0] : t2[1];
        float s = mine1 + __shfl_xor(theirs1, 4, 64);
        s += __shfl_xor(s, 2, 64);
        s += __shfl_xor(s, 1, 64);

        if ((lane & 3) == 0) {
            float rv = s + biasv;
            OUT[((p * NCOUT + (lane >> 2)) * NN + i) * NN + j] = rv > 0.f ? rv : 0.f;
        }
    }
}

extern "C" void kernel_launch(void* const* d_in, const int* in_sizes, int n_in,
                              void* d_out, int out_size, void* d_ws, size_t ws_size,
                              hipStream_t stream) {
    const float* FW   = (const float*)d_in[0]; // features_weighted (P,CIN,N,N,X)
    const float* PF   = (const float*)d_in[1]; // pair_features (P,T,N,X)
    const float* W0   = (const float*)d_in[2]; // (T,CIN,COUT)
    const float* W1   = (const float*)d_in[3]; // (T,CIN,COUT)
    const float* BIAS = (const float*)d_in[4]; // (COUT,1,1)
    float* OUT = (float*)d_out;                // (P,COUT,N,N)

    hipLaunchKernelGGL(higher_point_kernel, dim3(NP * NN), dim3(256), 0, stream,
                       FW, PF, W0, W1, BIAS, OUT);
}